// Round 7
// baseline (393.666 us; speedup 1.0000x reference)
//
#include <hip/hip_runtime.h>

#define NA 51
#define ROWS 64                       // one wave per block
#define GUARD 56                      // floats of guard each side (k clamped to +/-52)
#define NDATA (ROWS * NA)             // 3264 floats = 13056 B
#define BUFSZ (GUARD + NDATA + GUARD) // 3376 floats = 13504 B
#define KCLAMP 52
#define NBLK 1536                     // 6 blocks/CU x 256 CU (2x13504 B LDS -> 6 blocks/CU)

// native 16B vector type (HIP float4 is a class; this keeps 16B-aligned codegen)
typedef float v4 __attribute__((ext_vector_type(4), aligned(16)));

// counted vmcnt wait + scheduler fence (rule #18: stop reg-only hoisting past asm)
#define WAITV(N) do { asm volatile("s_waitcnt vmcnt(" #N ")" ::: "memory"); \
                      __builtin_amdgcn_sched_barrier(0); } while (0)

// C51 Bellman projection, persistent single-wave blocks, double-buffered LDS.
//   s = reward*2.5, k = floor(s) clamped to +/-52 (equivalent), f = frac(s)
//   out[i] = (1-f)*p[i-k]*[0<=i-k<=50] + f*p[i-k-1]*[...] + (i==0)*m_lo + (i==50)*m_hi
//
// Pipeline per half: issue the NEXT tile's 14 vmem LOADS (1 reward + 13
// global_load_lds) into the other buffer, then WAITV(14). vmcnt retires in
// order only AMONG READS (stores may complete OoO w.r.t. reads), so the only
// safe counted wait is <= newest-group-size: vmcnt(14) bounds total
// outstanding <= 14, hence outstanding LOADS are a suffix of <= 14 = exactly
// the next tile's group -> current tile's loads provably complete. This also
// forces the previous tile's 13 stores retired — which is why stores MUST be
// plain (retire at L2, ~200cy), NOT nontemporal (retire at HBM, ~900cy+queue):
// round-6 A/B showed nt stores cost +50% kernel time AND 1.85x write
// amplification (WRITE_SIZE 199->369 MB) from bypassed L2 write-combining.
// Two DISTINCT __shared__ arrays so alias analysis can't insert a
// conservative drain between prefetch(bufB) and ds_read(bufA).
// Copy-out keeps the coalesced LDS->float4 transpose (round-3 lesson: lane-
// major register stores = 4.6x write amplification).
__global__ __launch_bounds__(ROWS, 2) void c51_bellman_kernel(
    const float* __restrict__ reward,
    const float* __restrict__ probs,
    float* __restrict__ out,
    int bs)
{
    __shared__ __align__(16) float bufA[BUFSZ];
    __shared__ __align__(16) float bufB[BUFSZ];
    float* const dA = bufA + GUARD;   // GUARD*4 = 224 B -> 16B-aligned data
    float* const dB = bufB + GUARD;
    const int tid   = threadIdx.x;
    const int gs    = gridDim.x;
    const int nfull = bs / ROWS;      // full 64-row tiles
    const int rem   = bs - nfull * ROWS;

    // ---- helpers (inlined) ----
    auto issueL = [&](long tile, float* dst) {
        const char* src = (const char*)probs + (size_t)tile * (NDATA * 4);
        #pragma unroll
        for (int c = 0; c < 12; ++c) {
            __builtin_amdgcn_global_load_lds(
                (const __attribute__((address_space(1))) void*)
                    (unsigned long long)(src + c * 1024 + tid * 16),
                (__attribute__((address_space(3))) void*)
                    (unsigned long long)(dst + c * 256),
                16, 0, 0);
        }
        // tail 768 B = 48 lanes x 16 B, exec-masked single instruction
        if (tid < 48) {
            __builtin_amdgcn_global_load_lds(
                (const __attribute__((address_space(1))) void*)
                    (unsigned long long)(src + 12288 + tid * 16),
                (__attribute__((address_space(3))) void*)
                    (unsigned long long)(dst + 3072),
                16, 0, 0);
        }
    };

    auto computeT = [&](float* data, float rw) {
        const float s  = rw * 2.5f;          // r / 0.4
        const float kf = floorf(s);
        const float f  = s - kf;
        int k = (int)kf;
        k = min(max(k, -KCLAMP), KCLAMP);    // out-of-range k: all terms zero anyway
        const float* rp = data + tid * NA;   // lane stride 51 (odd) -> conflict-free

        // pass A: clamp masses
        float m_lo = 0.0f, m_hi = 0.0f;
        #pragma unroll
        for (int j = 0; j < NA; ++j) {
            const float pj = rp[j];
            const float t  = (float)j + s;
            if (t < 0.0f)  m_lo += pj;
            if (t > 50.0f) m_hi += pj;
        }

        // pass B: guarded window w[m] = p[m-k-1] (garbage in guards, masked below).
        // Whole window read before any write; single wave => in-order DS makes
        // all lanes' reads complete before any lane's in-place writes.
        const float* wb = rp - k - 1;
        float w[52];
        #pragma unroll
        for (int m = 0; m < 52; ++m) w[m] = wb[m];

        float* wp = data + tid * NA;
        const float w1 = 1.0f - f;
        float prev = ((unsigned)(-k - 1) <= 50u) ? w[0] : 0.0f;
        #pragma unroll
        for (int i = 0; i < NA; ++i) {
            const float cur = ((unsigned)(i - k) <= 50u) ? w[i + 1] : 0.0f;
            float o;
            if (i == 0)           o = w1 * cur + m_lo;
            else if (i == NA - 1) o = ((f == 0.0f) ? cur : f * prev) + m_hi;
            else                  o = w1 * cur + f * prev;
            wp[i] = o;                        // own row only; reads already issued
            prev = cur;
        }
    };

    auto storeT = [&](const float* data, long tile) {
        const v4* l4 = (const v4*)data;
        v4* o4 = (v4*)(out + (size_t)tile * NDATA);
        #pragma unroll
        for (int m = 0; m < 12; ++m)
            o4[m * 64 + tid] = l4[m * 64 + tid];      // plain: retire at L2
        if (tid < 48)                                 // 816 float4 = 12*64 + 48
            o4[768 + tid] = l4[768 + tid];
    };

    // ---- persistent double-buffered pipeline over full tiles ----
    long t = blockIdx.x;
    if (t < nfull) {
        float rwA = reward[t * ROWS + tid];
        issueL(t, dA);
        for (;;) {
            // --- half A: tile t resident in bufA ---
            const long tB = t + gs;
            const bool hB = tB < nfull;
            float rwB = 0.0f;
            if (hB) { rwB = reward[tB * ROWS + tid]; issueL(tB, dB); WAITV(14); }
            else    { WAITV(0); }
            computeT(dA, rwA);
            storeT(dA, t);
            if (!hB) break;

            // --- half B: tile tB resident in bufB ---
            const long tA2 = tB + gs;
            const bool hA = tA2 < nfull;
            if (hA) { rwA = reward[tA2 * ROWS + tid]; issueL(tA2, dA); WAITV(14); }
            else    { WAITV(0); }
            computeT(dB, rwB);
            storeT(dB, tB);
            if (!hA) break;
            t = tA2;
        }
    }

    // ---- ragged tail rows (bs % 64 != 0; unused at bs=1e6): block 0, lane/row ----
    if (rem && blockIdx.x == 0) {
        const int r = nfull * ROWS + tid;
        if (r < bs) {
            const float s  = reward[r] * 2.5f;
            const float kf = floorf(s);
            const float f  = s - kf;
            int k = (int)kf; k = min(max(k, -KCLAMP), KCLAMP);
            const float* rp = probs + (size_t)r * NA;
            float row[NA];
            #pragma unroll
            for (int j = 0; j < NA; ++j) row[j] = rp[j];
            float m_lo = 0.0f, m_hi = 0.0f;
            #pragma unroll
            for (int j = 0; j < NA; ++j) {
                const float tt = (float)j + s;
                if (tt < 0.0f)  m_lo += row[j];
                if (tt > 50.0f) m_hi += row[j];
            }
            float w[52];
            #pragma unroll
            for (int m = 0; m < 52; ++m)       // clamped index: masked-in slots unaffected
                w[m] = row[min(max(m - k - 1, 0), NA - 1)];
            float* op = out + (size_t)r * NA;
            const float w1 = 1.0f - f;
            float prev = ((unsigned)(-k - 1) <= 50u) ? w[0] : 0.0f;
            #pragma unroll
            for (int i = 0; i < NA; ++i) {
                const float cur = ((unsigned)(i - k) <= 50u) ? w[i + 1] : 0.0f;
                float o;
                if (i == 0)           o = w1 * cur + m_lo;
                else if (i == NA - 1) o = ((f == 0.0f) ? cur : f * prev) + m_hi;
                else                  o = w1 * cur + f * prev;
                op[i] = o;
                prev = cur;
            }
        }
    }
}

extern "C" void kernel_launch(void* const* d_in, const int* in_sizes, int n_in,
                              void* d_out, int out_size, void* d_ws, size_t ws_size,
                              hipStream_t stream) {
    const float* reward = (const float*)d_in[0];
    const float* probs  = (const float*)d_in[1];
    // d_in[2] = atom_values: unused — atom j sits exactly at index j in idx-space
    float* out = (float*)d_out;
    const int bs = in_sizes[0];

    const int nfull = bs / ROWS;
    int blocks = nfull < NBLK ? nfull : NBLK;
    if (blocks < 1) blocks = 1;   // bs < 64: tail path only
    c51_bellman_kernel<<<blocks, ROWS, 0, stream>>>(reward, probs, out, bs);
}

// Round 8
// 351.026 us; speedup vs baseline: 1.1215x; 1.1215x over previous
//
#include <hip/hip_runtime.h>

#define NA 51
#define ROWS 64                       // one wave per block
#define GUARD 56                      // floats of guard each side (k clamped to +/-52)
#define NDATA (ROWS * NA)             // 3264 floats = 13056 B
#define BUFSZ (GUARD + NDATA + GUARD) // 3376 floats = 13504 B -> 13568 alloc
#define KCLAMP 52
#define NBLK 2048                     // 8 blocks/CU x 256 CU (13568 B x 8 = 108.5 KB LDS/CU)

// native 16B vector type (HIP float4 is a class; this keeps 16B-aligned codegen)
typedef float v4 __attribute__((ext_vector_type(4), aligned(16)));

// counted vmcnt wait + scheduler fence (rule #18: stop reg-only hoisting past asm)
#define WAITV(N) do { asm volatile("s_waitcnt vmcnt(" #N ")" ::: "memory"); \
                      __builtin_amdgcn_sched_barrier(0); } while (0)

// C51 Bellman projection, persistent single-wave blocks, SINGLE LDS buffer,
// double-buffered via REGISTERS (T14 async-STAGE split).
//   s = reward*2.5, k = floor(s) clamped to +/-52 (equivalent), f = frac(s)
//   out[i] = (1-f)*p[i-k]*[0<=i-k<=50] + f*p[i-k-1]*[...] + (i==0)*m_lo + (i==50)*m_hi
//
// Round-6/7 lessons baked in:
//  * 27 KB LDS double-buffer halved CU concurrency (measured occupancy 10.5%
//    = 3.4 waves/CU vs r2's 30% at 13.5 KB) — so the second buffer is VGPRs:
//    prefetch tile t+1 into 13 v4 regs issued BEFORE compute of tile t; after
//    compute+store, WAITV(13) (13 newest outstanding = tile t's stores; the
//    prefetch loads are older => retired) then 13 ds_write_b128 into the one
//    buffer. Never vmcnt(0) in steady state; ~2000 cy of compute+store hides
//    the HBM latency of the prefetch.
//  * Stores plain (nt gave +1.85x WRITE amplification AND slower retirement).
//  * In-place LDS overwrite is safe: DS pipe processes one wave's LDS ops in
//    order, so storeT's ds_reads of tile t complete before writePF's ds_writes
//    of tile t+1 land (same assumption as r2's in-place pass B, verified).
__global__ __launch_bounds__(ROWS, 2) void c51_bellman_kernel(
    const float* __restrict__ reward,
    const float* __restrict__ probs,
    float* __restrict__ out,
    int bs)
{
    __shared__ __align__(16) float buf[BUFSZ];
    float* const data = buf + GUARD;  // GUARD*4 = 224 B -> 16B-aligned data
    const int tid   = threadIdx.x;
    const int gs    = gridDim.x;
    const int nfull = bs / ROWS;      // full 64-row tiles
    const int rem   = bs - nfull * ROWS;

    v4 pf[13];                        // prefetch regs, all indices static
    float rwPf = 0.0f;

    // issue NEXT tile's 14 vmem loads: 12 full dwordx4 + 1 masked (48 lanes)
    // + reward. Counts exactly 14 vmcnt ops.
    auto issuePF = [&](long tile) {
        const v4* s4 = (const v4*)(probs + (size_t)tile * NDATA);
        #pragma unroll
        for (int c = 0; c < 12; ++c) pf[c] = s4[c * 64 + tid];
        if (tid < 48) pf[12] = s4[768 + tid];      // tail 768 B of the 13056 B tile
        rwPf = reward[tile * ROWS + tid];
    };
    // reg -> LDS, identity layout (13 ds_write_b128)
    auto writePF = [&]() {
        v4* d4 = (v4*)data;
        #pragma unroll
        for (int c = 0; c < 12; ++c) d4[c * 64 + tid] = pf[c];
        if (tid < 48) d4[768 + tid] = pf[12];
    };

    auto computeT = [&](float rw) {
        const float s  = rw * 2.5f;          // r / 0.4
        const float kf = floorf(s);
        const float f  = s - kf;
        int k = (int)kf;
        k = min(max(k, -KCLAMP), KCLAMP);    // out-of-range k: all terms zero anyway
        const float* rp = data + tid * NA;   // lane stride 51 (odd) -> conflict-free

        // pass A: clamp masses
        float m_lo = 0.0f, m_hi = 0.0f;
        #pragma unroll
        for (int j = 0; j < NA; ++j) {
            const float pj = rp[j];
            const float t  = (float)j + s;
            if (t < 0.0f)  m_lo += pj;
            if (t > 50.0f) m_hi += pj;
        }

        // pass B: guarded window w[m] = p[m-k-1] (garbage in guards, masked below).
        // Whole window read before any in-place write; in-order DS per wave.
        const float* wb = rp - k - 1;
        float w[52];
        #pragma unroll
        for (int m = 0; m < 52; ++m) w[m] = wb[m];

        float* wp = data + tid * NA;
        const float w1 = 1.0f - f;
        float prev = ((unsigned)(-k - 1) <= 50u) ? w[0] : 0.0f;
        #pragma unroll
        for (int i = 0; i < NA; ++i) {
            const float cur = ((unsigned)(i - k) <= 50u) ? w[i + 1] : 0.0f;
            float o;
            if (i == 0)           o = w1 * cur + m_lo;
            else if (i == NA - 1) o = ((f == 0.0f) ? cur : f * prev) + m_hi;
            else                  o = w1 * cur + f * prev;
            wp[i] = o;                        // own row only; reads already issued
            prev = cur;
        }
    };

    // coalesced LDS -> global, exactly 13 store instructions (vmcnt accounting)
    auto storeT = [&](long tile) {
        const v4* l4 = (const v4*)data;
        v4* o4 = (v4*)(out + (size_t)tile * NDATA);
        #pragma unroll
        for (int m = 0; m < 12; ++m)
            o4[m * 64 + tid] = l4[m * 64 + tid];      // plain: retire at L2
        if (tid < 48)                                 // 816 float4 = 12*64 + 48
            o4[768 + tid] = l4[768 + tid];
    };

    // ---- persistent pipeline: one LDS buffer, reg-prefetch depth 1 ----
    long t = blockIdx.x;
    if (t < nfull) {
        issuePF(t);
        WAITV(0);                    // prologue only
        writePF();
        float rwCur = rwPf;
        for (;;) {
            const long tn = t + gs;
            const bool hN = tn < nfull;
            if (hN) issuePF(tn);     // 14 loads in flight across compute+store
            computeT(rwCur);         // LDS + VALU only
            storeT(t);               // 13 plain stores (newest vmem ops)
            if (!hN) break;
            WAITV(13);               // <=13 outstanding = the 13 stores; loads done
            writePF();               // overwrite LDS with tile tn (in-order DS)
            rwCur = rwPf;
            t = tn;
        }
    }

    // ---- ragged tail rows (bs % 64 != 0; unused at bs=1e6): block 0, lane/row ----
    if (rem && blockIdx.x == 0) {
        const int r = nfull * ROWS + tid;
        if (r < bs) {
            const float s  = reward[r] * 2.5f;
            const float kf = floorf(s);
            const float f  = s - kf;
            int k = (int)kf; k = min(max(k, -KCLAMP), KCLAMP);
            const float* rp = probs + (size_t)r * NA;
            float row[NA];
            #pragma unroll
            for (int j = 0; j < NA; ++j) row[j] = rp[j];
            float m_lo = 0.0f, m_hi = 0.0f;
            #pragma unroll
            for (int j = 0; j < NA; ++j) {
                const float tt = (float)j + s;
                if (tt < 0.0f)  m_lo += row[j];
                if (tt > 50.0f) m_hi += row[j];
            }
            float w[52];
            #pragma unroll
            for (int m = 0; m < 52; ++m)       // clamped index: masked-in slots unaffected
                w[m] = row[min(max(m - k - 1, 0), NA - 1)];
            float* op = out + (size_t)r * NA;
            const float w1 = 1.0f - f;
            float prev = ((unsigned)(-k - 1) <= 50u) ? w[0] : 0.0f;
            #pragma unroll
            for (int i = 0; i < NA; ++i) {
                const float cur = ((unsigned)(i - k) <= 50u) ? w[i + 1] : 0.0f;
                float o;
                if (i == 0)           o = w1 * cur + m_lo;
                else if (i == NA - 1) o = ((f == 0.0f) ? cur : f * prev) + m_hi;
                else                  o = w1 * cur + f * prev;
                op[i] = o;
                prev = cur;
            }
        }
    }
}

extern "C" void kernel_launch(void* const* d_in, const int* in_sizes, int n_in,
                              void* d_out, int out_size, void* d_ws, size_t ws_size,
                              hipStream_t stream) {
    const float* reward = (const float*)d_in[0];
    const float* probs  = (const float*)d_in[1];
    // d_in[2] = atom_values: unused — atom j sits exactly at index j in idx-space
    float* out = (float*)d_out;
    const int bs = in_sizes[0];

    const int nfull = bs / ROWS;
    int blocks = nfull < NBLK ? nfull : NBLK;
    if (blocks < 1) blocks = 1;   // bs < 64: tail path only
    c51_bellman_kernel<<<blocks, ROWS, 0, stream>>>(reward, probs, out, bs);
}

// Round 9
// 347.332 us; speedup vs baseline: 1.1334x; 1.0106x over previous
//
#include <hip/hip_runtime.h>

#define NA 51
#define TPB 128                 // 2 independent waves per block (no barriers anywhere)
#define WROWS 64                // rows per wave
#define KCLAMP 52

// 4B-aligned vector for global per-lane loads (row base = r*204 B, only 4B-aligned)
typedef float v4u __attribute__((ext_vector_type(4), aligned(4)));
typedef float v2u __attribute__((ext_vector_type(2), aligned(4)));
// 16B-aligned vector for LDS reads / coalesced global stores
typedef float v4a __attribute__((ext_vector_type(4), aligned(16)));

// C51 Bellman projection, thread-per-row, register compute + LDS OUTPUT transpose.
//   s = reward*2.5, k = floor(s) clamped to +/-52 (equivalent), f = frac(s)
//   out[i] = (1-f)*p[i-k]*[0<=i-k<=50] + f*p[i-k-1]*[...] + (i==0)*m_lo + (i==50)*m_hi
//
// Consolidated lessons:
//  * r3: per-lane REGISTER LOADS are traffic-exact (a wave's 64 rows span one
//    contiguous 13 KB block -> every 64B line fully consumed; FETCH stayed
//    ~103 MB) but per-lane STORES amplify writes 4.6x -> output must go
//    through an LDS transpose. This kernel uses registers for input,
//    LDS only for output.
//  * r2 vs r6/7/8: non-persistent dispatch-ordered grids give bit-exact
//    WRITE_SIZE (199218.75 KB every run); persistent grids inflate it 1.85x.
//    Non-persistent it is.
//  * r7: fillBuffer does 6.5 TB/s at 10% occupancy -> BW needs MLP, not waves.
//    Here each lane issues 26 independent loads with no vmcnt(0) drain and no
//    LDS-input round-trip; compiler waits per-register as values are consumed.
//  * LDS out-staging: lane-stride 51 (odd) scalar writes -> (19*lane+i)%32
//    covers each bank exactly 2x per wave = free (m136). Copy-out b128 reads
//    are wave-private (DS pipe is in-order per wave -> no barrier, no fence).
__global__ __launch_bounds__(TPB, 3) void c51_bellman_kernel(
    const float* __restrict__ reward,
    const float* __restrict__ probs,
    float* __restrict__ out,
    int bs)
{
    __shared__ __align__(16) float lds[TPB * NA];   // 26112 B -> 6 blocks/CU
    const int tid   = threadIdx.x;
    const int lane  = tid & 63;
    const int wv    = tid >> 6;
    const int wrow0 = blockIdx.x * TPB + wv * WROWS;   // wave's first row
    const int r     = wrow0 + lane;
    const bool edge = (blockIdx.x == 0) | (blockIdx.x == (int)gridDim.x - 1);

    float* const wlds = lds + wv * (WROWS * NA);       // wave-private 13056 B
    const int nrows_w = min(WROWS, max(0, bs - wrow0));

    if (lane < nrows_w) {
        const float s  = reward[r] * 2.5f;   // r / 0.4
        const float kf = floorf(s);
        const float f  = s - kf;
        int k = (int)kf;
        k = min(max(k, -KCLAMP), KCLAMP);    // out-of-range k: all terms zero anyway
        const float* rp = probs + (size_t)r * NA;

        // ---- own row -> regs (12 x dwordx4 + dwordx2 + dword, 4B-aligned) ----
        float row[NA];
        #pragma unroll
        for (int c = 0; c < 12; ++c) *(v4u*)&row[4 * c] = *(const v4u*)&rp[4 * c];
        *(v2u*)&row[48] = *(const v2u*)&rp[48];
        row[50] = rp[50];

        // ---- gather window w[m] = p[m-k-1] -> regs (13 x dwordx4) ----
        // Strays at most 212 B outside the row: safe except for the tensor's
        // first/last rows -> first/last BLOCK (uniform branch) clamps per
        // element into its own row (masked-in slots have a no-op clamp).
        float w[52];
        if (!edge) {
            const float* wb = rp - k - 1;
            #pragma unroll
            for (int c = 0; c < 13; ++c) *(v4u*)&w[4 * c] = *(const v4u*)&wb[4 * c];
        } else {
            #pragma unroll
            for (int m = 0; m < 52; ++m)
                w[m] = rp[min(max(m - k - 1, 0), NA - 1)];
        }

        // ---- clamp masses from the row regs ----
        float m_lo = 0.0f, m_hi = 0.0f;
        #pragma unroll
        for (int j = 0; j < NA; ++j) {
            const float t = (float)j + s;
            if (t < 0.0f)  m_lo += row[j];
            if (t > 50.0f) m_hi += row[j];
        }

        // ---- projection; write each atom straight to wave-private LDS ----
        //   w1 = (i+f<=50)?1-f:0  ->  1-f for i<50;  (f==0)?1:0 at i=50
        //   w2 = (i-1+f>=0)?f:0   ->  0 at i==0;     f for i>=1
        float* wp = wlds + lane * NA;
        const float w1 = 1.0f - f;
        float prev = ((unsigned)(-k - 1) <= 50u) ? w[0] : 0.0f;
        #pragma unroll
        for (int i = 0; i < NA; ++i) {
            const float cur = ((unsigned)(i - k) <= 50u) ? w[i + 1] : 0.0f;
            float o;
            if (i == 0)           o = w1 * cur + m_lo;
            else if (i == NA - 1) o = ((f == 0.0f) ? cur : f * prev) + m_hi;
            else                  o = w1 * cur + f * prev;
            wp[i] = o;
            prev = cur;
        }
    }

    // ---- copy-out: wave-private LDS -> coalesced 16B stores (no barrier:
    // DS ops of a wave execute in order, so these reads see the writes) ----
    const int nelem = nrows_w * NA;
    const int n4    = nelem >> 2;
    const v4a* l4 = (const v4a*)wlds;                       // wave base: 16B-aligned
    v4a* o4 = (v4a*)(out + (size_t)wrow0 * NA);             // wrow0*51 % 4 == 0
    for (int e = lane; e < n4; e += 64) o4[e] = l4[e];      // plain: retire at L2
    for (int e = (n4 << 2) + lane; e < nelem; e += 64)
        out[(size_t)wrow0 * NA + e] = wlds[e];
}

extern "C" void kernel_launch(void* const* d_in, const int* in_sizes, int n_in,
                              void* d_out, int out_size, void* d_ws, size_t ws_size,
                              hipStream_t stream) {
    const float* reward = (const float*)d_in[0];
    const float* probs  = (const float*)d_in[1];
    // d_in[2] = atom_values: unused — atom j sits exactly at index j in idx-space
    float* out = (float*)d_out;
    const int bs = in_sizes[0];

    const int blocks = (bs + TPB - 1) / TPB;
    c51_bellman_kernel<<<blocks, TPB, 0, stream>>>(reward, probs, out, bs);
}

// Round 10
// 341.194 us; speedup vs baseline: 1.1538x; 1.0180x over previous
//
#include <hip/hip_runtime.h>

#define NA 51
#define TPB 256
#define RPW 16            // rows per wave (4 lanes collaborate on one row)
#define RPB 64            // rows per block (4 waves)
#define KCLAMP 52

// 4B-aligned vectors for per-lane global loads (bases are only 4B-aligned)
typedef float v4u __attribute__((ext_vector_type(4), aligned(4)));
typedef float v2u __attribute__((ext_vector_type(2), aligned(4)));
// 16B-aligned vector for LDS reads / coalesced global stores
typedef float v4a __attribute__((ext_vector_type(4), aligned(16)));

// C51 Bellman projection, QUAD-LANE rows: lane q in [0,4) of a row computes
// atoms [13q, 13q+12] (12 atoms for q=3). s = reward*2.5, k = floor(s)
// clamped to +/-52 (equivalent), f = frac(s):
//   out[i] = (1-f)*p[i-k]*[0<=i-k<=50] + f*p[i-k-1]*[...] + (i==0)*m_lo + (i==50)*m_hi
//
// Why thin waves: r2/r8/r9 (64 rows/wave, 3 different memory pipelines) all
// plateau at ~115 us with ~22% VALUBusy and <=12 waves/CU — latency-hiding
// bound, not pipe bound. This shape cuts per-wave state to ~45 VGPR + 3.26 KB
// LDS -> 32 waves/CU (HW cap, 2.7x more) with 4x shorter per-tile chains.
// Masses are a 2-step __shfl_xor quad-reduce; input loads are per-lane
// contiguous (traffic-exact: a wave's reads span its own ~4 KB row block);
// output goes through wave-private LDS (r3: lane-major global stores = 4.6x
// write amplification) and out as coalesced b128 — plain stores (r6: nt =
// 1.85x write amplification). No barriers anywhere (DS in-order per wave).
__global__ __launch_bounds__(TPB, 8) void c51_bellman_kernel(
    const float* __restrict__ reward,
    const float* __restrict__ probs,
    float* __restrict__ out,
    int bs)
{
    __shared__ __align__(16) float lds[4][RPW * NA];   // 4 waves x 3264 B = 13056 B
    const int tid  = threadIdx.x;
    const int lane = tid & 63;
    const int wv   = tid >> 6;
    const int q    = lane & 3;          // slot within the row's quad
    const int lr   = lane >> 2;         // local row within the wave
    const int wrow0 = blockIdx.x * RPB + wv * RPW;
    const int r     = wrow0 + lr;
    const bool edge = (blockIdx.x == 0) | (blockIdx.x == (int)gridDim.x - 1);

    float* const wlds = lds[wv];
    const int a0    = 13 * q;               // first atom of my slice
    const int count = (q < 3) ? 13 : 12;    // atoms in my slice

    if (r < bs) {
        const float s  = reward[r] * 2.5f;  // r / 0.4 (same addr across quad)
        const float kf = floorf(s);
        const float f  = s - kf;
        int k = (int)kf;
        k = min(max(k, -KCLAMP), KCLAMP);   // out-of-range k: all terms zero anyway
        const float* rp = probs + (size_t)r * NA;

        // ---- my row slice -> regs (always in-row; q=3 pads with 0) ----
        float row[13];
        *(v4u*)&row[0] = *(const v4u*)&rp[a0];
        *(v4u*)&row[4] = *(const v4u*)&rp[a0 + 4];
        *(v4u*)&row[8] = *(const v4u*)&rp[a0 + 8];
        row[12] = (q < 3) ? rp[a0 + 12] : 0.0f;

        // ---- gather window w[m] = p[a0 + m - k - 1], m in [0,14) ----
        // Strays at most 212 B before / ~420 B after the row: unsafe only for
        // rows {0,1} and {bs-2,bs-1} -> first/last BLOCK (uniform branch)
        // clamps per element into the row (no-op clamp for masked-in slots).
        float w[14];
        if (!edge) {
            const float* wb = rp + a0 - k - 1;
            *(v4u*)&w[0]  = *(const v4u*)&wb[0];
            *(v4u*)&w[4]  = *(const v4u*)&wb[4];
            *(v4u*)&w[8]  = *(const v4u*)&wb[8];
            *(v2u*)&w[12] = *(const v2u*)&wb[12];
        } else {
            #pragma unroll
            for (int m = 0; m < 14; ++m)
                w[m] = rp[min(max(a0 + m - k - 1, 0), NA - 1)];
        }

        // ---- clamp masses: partial over my slice, then quad-reduce ----
        float m_lo = 0.0f, m_hi = 0.0f;
        #pragma unroll
        for (int c = 0; c < 13; ++c) {
            const float t = (float)(a0 + c) + s;   // q=3,c=12: row[12]=0, harmless
            if (t < 0.0f)  m_lo += row[c];
            if (t > 50.0f) m_hi += row[c];
        }
        m_lo += __shfl_xor(m_lo, 1, 64); m_lo += __shfl_xor(m_lo, 2, 64);
        m_hi += __shfl_xor(m_hi, 1, 64); m_hi += __shfl_xor(m_hi, 2, 64);

        // ---- projection: w[c] = p[i-k-1], w[c+1] = p[i-k] for i = a0+c ----
        //   i==0  (q0,c0):  o = (1-f)*cur + m_lo            (w2=0 at i=0)
        //   i==50 (q3,c11): o = (f==0 ? cur : f*prev) + m_hi
        //   else:           o = (1-f)*cur + f*prev
        const float w1 = 1.0f - f;
        float* wp = wlds + lr * NA + a0;
        #pragma unroll
        for (int c = 0; c < 13; ++c) {
            const int i = a0 + c;
            const float pl = ((unsigned)(i - k - 1) <= 50u) ? w[c]     : 0.0f;
            const float cu = ((unsigned)(i - k)     <= 50u) ? w[c + 1] : 0.0f;
            float o;
            if (i == 0)           o = w1 * cu + m_lo;
            else if (i == NA - 1) o = ((f == 0.0f) ? cu : f * pl) + m_hi;
            else                  o = w1 * cu + f * pl;
            if (c < count) wp[c] = o;   // q=3,c=12 would alias next row's atom 0
        }
    }

    // ---- copy-out: wave-private LDS -> coalesced 16B stores (no barrier:
    // a wave's DS ops execute in order, so these reads see its writes) ----
    const int nrw   = min(RPW, max(0, bs - wrow0));
    const int nelem = nrw * NA;                       // 816 floats when full
    const int n4    = nelem >> 2;
    const v4a* l4 = (const v4a*)wlds;                 // wave base 3264B-aligned
    v4a* o4 = (v4a*)(out + (size_t)wrow0 * NA);       // wrow0*51*4 % 16 == 0
    for (int e = lane; e < n4; e += 64) o4[e] = l4[e];        // plain stores
    for (int e = (n4 << 2) + lane; e < nelem; e += 64)
        out[(size_t)wrow0 * NA + e] = wlds[e];
}

extern "C" void kernel_launch(void* const* d_in, const int* in_sizes, int n_in,
                              void* d_out, int out_size, void* d_ws, size_t ws_size,
                              hipStream_t stream) {
    const float* reward = (const float*)d_in[0];
    const float* probs  = (const float*)d_in[1];
    // d_in[2] = atom_values: unused — atom j sits exactly at index j in idx-space
    float* out = (float*)d_out;
    const int bs = in_sizes[0];

    const int blocks = (bs + RPB - 1) / RPB;
    c51_bellman_kernel<<<blocks, TPB, 0, stream>>>(reward, probs, out, bs);
}